// Round 6
// baseline (120.459 us; speedup 1.0000x reference)
//
#include <hip/hip_runtime.h>

typedef __attribute__((ext_vector_type(8))) short s16x8;
typedef __attribute__((ext_vector_type(4))) float f32x4;
typedef __attribute__((ext_vector_type(4))) unsigned int u32x4;
typedef __attribute__((ext_vector_type(2))) unsigned int u32x2;
typedef unsigned short u16;
typedef unsigned int u32;
typedef unsigned long long u64;

__device__ __forceinline__ u16 f2bf(float f) {
  u32 u = __float_as_uint(f);
  u32 r = u + 0x7fffu + ((u >> 16) & 1u);
  return (u16)(r >> 16);
}
__device__ __forceinline__ float bf2f(u16 h) {
  return __uint_as_float(((u32)h) << 16);
}

typedef __attribute__((address_space(3))) char lds_char_t;
typedef __attribute__((address_space(1))) const char glb_char_t;
__device__ __forceinline__ void gl2lds16(const void* g, void* l) {
  __builtin_amdgcn_global_load_lds((glb_char_t*)g, (lds_char_t*)l, 16, 0, 0);
}

#define HS_N 3145728   // 4096*768
#define W_N  589824    // 768*768
#define LOG2E 1.44269504f

// ---------------- K0: f32 -> bf16 conversions + bias concat ----------------
__global__ __launch_bounds__(256) void convert_kernel(
    const float* __restrict__ hs, const float* __restrict__ wq, const float* __restrict__ wk,
    const float* __restrict__ wv, const float* __restrict__ wo,
    const float* __restrict__ bq, const float* __restrict__ bk, const float* __restrict__ bv,
    u16* __restrict__ hsb, u16* __restrict__ wqkvb, u16* __restrict__ wob,
    float* __restrict__ biasqkv)
{
  int t = blockIdx.x * 256 + threadIdx.x;
  long i = (long)t * 8;
  const float* src;
  u16* dst;
  if (i < HS_N)              { src = hs + i;                  dst = hsb + i; }
  else if (i < HS_N + W_N)   { src = wq + (i - HS_N);         dst = wqkvb + (i - HS_N); }
  else if (i < HS_N + 2*W_N) { src = wk + (i - HS_N - W_N);   dst = wqkvb + (i - HS_N); }
  else if (i < HS_N + 3*W_N) { src = wv + (i - HS_N - 2*W_N); dst = wqkvb + (i - HS_N); }
  else                       { src = wo + (i - HS_N - 3*W_N); dst = wob + (i - HS_N - 3*W_N); }
  float4 a = ((const float4*)src)[0];
  float4 b = ((const float4*)src)[1];
  uint4 o;
  o.x = (u32)f2bf(a.x) | ((u32)f2bf(a.y) << 16);
  o.y = (u32)f2bf(a.z) | ((u32)f2bf(a.w) << 16);
  o.z = (u32)f2bf(b.x) | ((u32)f2bf(b.y) << 16);
  o.w = (u32)f2bf(b.z) | ((u32)f2bf(b.w) << 16);
  *(uint4*)dst = o;
  if (t < 2304) biasqkv[t] = (t < 768) ? bq[t] : ((t < 1536) ? bk[t - 768] : bv[t - 1536]);
}

// ---------------- GEMM v2 (unchanged from R4): async-pipelined, C = A @ Bt^T + bias ----
template<int MODE>
__global__ __launch_bounds__(256, 2) void gemm_bt(
    const u16* __restrict__ A, const u16* __restrict__ Bt, const float* __restrict__ bias,
    float* __restrict__ outF, u16* __restrict__ Qb, u16* __restrict__ Kb, u16* __restrict__ Vtb)
{
  constexpr int NT = (MODE == 0) ? 18 : 6;
  constexpr int CPX = NT * 64 / 8;

  __shared__ __align__(16) char sm[73728];
  char* const smA = sm;
  char* const smB = sm + 24576;

  const int tid = threadIdx.x;
  const int lane = tid & 63;
  const int w = tid >> 6;
  const int l15 = lane & 15, g = lane >> 4;
  const int wid = (blockIdx.x & 7) * CPX + (blockIdx.x >> 3);
  const int bx = wid % NT, by = wid / NT;
  const int mBase = by * 64;
  const int nBase = bx * 128;
  const int wr = w >> 1, wc = w & 1;
  const int mW = wr * 32, nW = wc * 64;

  f32x4 zero = {0.f, 0.f, 0.f, 0.f};
  f32x4 acc[2][4];
  #pragma unroll
  for (int i = 0; i < 2; i++)
    #pragma unroll
    for (int j = 0; j < 4; j++) acc[i][j] = zero;

  const u16* Arow = A + (long)mBase * 768;
  const u16* Brow = Bt + (long)nBase * 768;

  auto stage = [&](int c, int kb) {
    const int k0 = c * 64;
    #pragma unroll
    for (int i = 0; i < 2; i++) {
      int o = (i * 256 + tid) * 16;
      int r = o >> 7;
      int sl = ((o >> 4) & 7) ^ (r & 7);
      gl2lds16(Arow + (long)r * 768 + k0 + sl * 8,
               smA + kb * 8192 + i * 4096 + w * 1024);
    }
    #pragma unroll
    for (int i = 0; i < 4; i++) {
      int o = (i * 256 + tid) * 16;
      int r = o >> 7;
      int sl = ((o >> 4) & 7) ^ (r & 7);
      gl2lds16(Brow + (long)r * 768 + k0 + sl * 8,
               smB + kb * 16384 + i * 4096 + w * 1024);
    }
  };

  auto compute = [&](int kb) {
    const char* bufA = smA + kb * 8192;
    const char* bufB = smB + kb * 16384;
    #pragma unroll
    for (int kh = 0; kh < 2; kh++) {
      s16x8 af[2], bf[4];
      #pragma unroll
      for (int mi = 0; mi < 2; mi++) {
        int R = mW + mi * 16 + l15;
        af[mi] = *(const s16x8*)(bufA + R * 128 + (((kh * 4 + g) ^ (l15 & 7)) << 4));
      }
      #pragma unroll
      for (int ni = 0; ni < 4; ni++) {
        int R = nW + ni * 16 + l15;
        bf[ni] = *(const s16x8*)(bufB + R * 128 + (((kh * 4 + g) ^ (l15 & 7)) << 4));
      }
      #pragma unroll
      for (int mi = 0; mi < 2; mi++)
        #pragma unroll
        for (int ni = 0; ni < 4; ni++)
          acc[mi][ni] = __builtin_amdgcn_mfma_f32_16x16x32_bf16(af[mi], bf[ni], acc[mi][ni], 0, 0, 0);
    }
  };

  auto body = [&](int c, int kb, int kbn) {
    if (c < 11) { stage(c + 1, kbn); asm volatile("s_waitcnt vmcnt(6)" ::: "memory"); }
    else        { asm volatile("s_waitcnt vmcnt(0)" ::: "memory"); }
    asm volatile("s_barrier" ::: "memory");
    compute(kb);
  };

  stage(0, 0);
  #pragma unroll 1
  for (int cc = 0; cc < 4; cc++) {
    body(cc * 3,     0, 1);
    body(cc * 3 + 1, 1, 2);
    body(cc * 3 + 2, 2, 0);
  }
  __syncthreads();

  const int b_ = mBase >> 10;
  const int s0b = mBase & 1023;

  if constexpr (MODE == 1) {
    #pragma unroll
    for (int mi = 0; mi < 2; mi++)
      #pragma unroll
      for (int ni = 0; ni < 4; ni++) {
        int n = nBase + nW + ni * 16 + l15;
        int m0 = mBase + mW + mi * 16 + g * 4;
        float bb = bias[n];
        outF[(long)m0 * 768 + n]       = acc[mi][ni][0] + bb;
        outF[(long)(m0 + 1) * 768 + n] = acc[mi][ni][1] + bb;
        outF[(long)(m0 + 2) * 768 + n] = acc[mi][ni][2] + bb;
        outF[(long)(m0 + 3) * 768 + n] = acc[mi][ni][3] + bb;
      }
  } else {
    const int typ = bx / 6;
    if (typ < 2) {
      u16* qk = (typ == 0) ? Qb : Kb;
      #pragma unroll
      for (int mi = 0; mi < 2; mi++)
        #pragma unroll
        for (int ni = 0; ni < 4; ni++) {
          int n = nBase + nW + ni * 16 + l15;
          int hn = n - typ * 768;
          int h = hn >> 6, d = hn & 63;
          long bh = (long)b_ * 12 + h;
          int s0 = s0b + mW + mi * 16 + g * 4;
          float bb = bias[n];
          u16* dst = qk + (bh << 16) + ((long)s0 << 6) + d;
          dst[0]   = f2bf(acc[mi][ni][0] + bb);
          dst[64]  = f2bf(acc[mi][ni][1] + bb);
          dst[128] = f2bf(acc[mi][ni][2] + bb);
          dst[192] = f2bf(acc[mi][ni][3] + bb);
        }
    } else {
      u16* ct = (u16*)sm;
      #pragma unroll
      for (int mi = 0; mi < 2; mi++)
        #pragma unroll
        for (int ni = 0; ni < 4; ni++) {
          int nr = nW + ni * 16 + l15;
          int mr = mW + mi * 16 + g * 4;
          float bb = bias[nBase + nr];
          u32 lo = (u32)f2bf(acc[mi][ni][0] + bb) | ((u32)f2bf(acc[mi][ni][1] + bb) << 16);
          u32 hi = (u32)f2bf(acc[mi][ni][2] + bb) | ((u32)f2bf(acc[mi][ni][3] + bb) << 16);
          *(u64*)(ct + nr * 72 + mr) = (u64)lo | ((u64)hi << 32);
        }
      __syncthreads();
      int dr = tid >> 1, part = tid & 1;
      int hn = (bx - 12) * 128 + dr;
      int h = hn >> 6, d = hn & 63;
      long bh = (long)b_ * 12 + h;
      u16* dst = Vtb + (bh << 16) + (d << 10) + s0b + part * 32;
      const u16* srl = ct + dr * 72 + part * 32;
      #pragma unroll
      for (int i = 0; i < 4; i++)
        *(uint4*)(dst + i * 8) = *(const uint4*)(srl + i * 8);
    }
  }
}

// ---------------- K2: extended features + beta (log2e folded for exp2) ----------------
// qAe[0:16)=0.25*log2e*qA, [16:80)=0.25e-3*log2e*q ; kAe[0:16)=kA, [16:80)=1e-3*k
// beta[t] = log2e * (-0.125*(|kA|^2 + 1e-6|k|^2) + mask)
__global__ __launch_bounds__(256) void qk_ext_kernel(
    const u16* __restrict__ Qb, const u16* __restrict__ Kb, const float* __restrict__ Am,
    const float* __restrict__ mask, u16* __restrict__ qAe, u16* __restrict__ kAe,
    float* __restrict__ beta2)
{
  const bool isK = blockIdx.x >= 192;
  const int rb = blockIdx.x * 256 - (isK ? 49152 : 0);
  const int h = (rb >> 10) % 12;
  const int row = rb + threadIdx.x;
  const int bh = row >> 10;
  const int s = row & 1023;
  const int b_ = bh / 12;

  const u16* src = (isK ? Kb : Qb) + ((long)row << 6);
  union { uint4 v4[8]; u32 u[32]; } c;
  #pragma unroll
  for (int i = 0; i < 8; i++) c.v4[i] = ((const uint4*)src)[i];

  const float* Ah = Am + h * 1024;
  float acc[16];
  #pragma unroll
  for (int r = 0; r < 16; r++) acc[r] = 0.f;
  float s2 = 0.f;
  #pragma unroll
  for (int d = 0; d < 64; d++) {
    u32 wd = c.u[d >> 1];
    float qd = bf2f((u16)((d & 1) ? (wd >> 16) : (wd & 0xffffu)));
    s2 += qd * qd;
    #pragma unroll
    for (int r = 0; r < 16; r++) acc[r] += qd * Ah[d * 16 + r];
  }

  union { u16 us[128]; uint4 v4[16]; } o;
  const float sA = isK ? 1.0f : 0.25f * LOG2E;
  const float sQ = isK ? 1e-3f : 0.25e-3f * LOG2E;
  #pragma unroll
  for (int r = 0; r < 16; r++) o.us[r] = f2bf(acc[r] * sA);
  #pragma unroll
  for (int d = 0; d < 64; d++) {
    u32 wd = c.u[d >> 1];
    float qd = bf2f((u16)((d & 1) ? (wd >> 16) : (wd & 0xffffu)));
    o.us[16 + d] = f2bf(qd * sQ);
  }
  #pragma unroll
  for (int j = 80; j < 128; j++) o.us[j] = 0;

  u16* dst = (isK ? kAe : qAe) + ((long)row << 7);
  #pragma unroll
  for (int i = 0; i < 16; i++) ((uint4*)dst)[i] = o.v4[i];

  if (isK) {
    float kk = 1e-6f * s2;
    #pragma unroll
    for (int r = 0; r < 16; r++) kk += acc[r] * acc[r];
    beta2[row] = LOG2E * (-0.125f * kk + mask[(b_ << 10) + s]);
  }
}

// ---------------- K3: attention v4 — barrier-free, all-register K/V ----------------
// grid 1536 = 48 bh x 32 qtiles(32 rows), XCD-swizzled; block = 1 wave (64 thr).
// Per chunk (32 t): 10 asm VMEM (K6 to regs, V4 to regs), double-buffered;
// waits vmcnt(14) [K landed] / vmcnt(10) [V landed], never 0 until last.
// Beta staged to LDS once in prologue (1024B per gl2lds16 instruction!).
// P round-trip via per-wave LDS (stride 80).
__global__ __launch_bounds__(64, 2) void attn_kernel(
    const u16* __restrict__ qAe, const u16* __restrict__ kAe, const u16* __restrict__ Vtb,
    const float* __restrict__ beta2, u16* __restrict__ ctxb)
{
  const int lane = threadIdx.x & 63;
  const int l15 = lane & 15, g = lane >> 4;
  const int wid = ((int)blockIdx.x & 7) * 192 + ((int)blockIdx.x >> 3);  // 1536=8*192
  const int bh = wid >> 5;
  const int q0 = (wid & 31) * 32;

  __shared__ __align__(16) char Pw[32 * 80];     // P: 32 q-rows x 64B (stride 80)
  __shared__ __align__(16) float Blds[1024];     // beta for this bh

  const u16* qbase = qAe + ((long)(bh * 1024 + q0) << 7);
  const u16* kbase = kAe + ((long)bh << 17);
  const u16* vbase = Vtb + ((long)bh << 16);
  const float* betab = beta2 + (bh << 10);

  // prologue VMEM order: bqv(6), beta->LDS(4), K0(6), V0(4)
  u32x4 bqv[2][3];
  #pragma unroll
  for (int qf = 0; qf < 2; qf++)
    #pragma unroll
    for (int ks = 0; ks < 3; ks++) {
      const u16* a = qbase + ((qf * 16 + l15) << 7) + ks * 32 + g * 8;
      asm volatile("global_load_dwordx4 %0, %1, off" : "=v"(bqv[qf][ks]) : "v"(a));
    }
  #pragma unroll
  for (int i = 0; i < 4; i++)
    gl2lds16(betab + i * 256 + lane * 4, (char*)Blds + i * 1024);   // FIX: 1024B/instr

  auto loadK = [&](int c, u32x4 (&dst)[6]) {
    const long t0 = (long)c * 32;
    #pragma unroll
    for (int tf = 0; tf < 2; tf++)
      #pragma unroll
      for (int ks = 0; ks < 3; ks++) {
        const u16* a = kbase + (t0 + tf * 16 + l15) * 128 + ks * 32 + g * 8;
        asm volatile("global_load_dwordx4 %0, %1, off" : "=v"(dst[tf * 3 + ks]) : "v"(a));
      }
  };
  auto loadV = [&](int c, u32x4 (&dst)[4]) {
    const int t0 = c * 32;
    #pragma unroll
    for (int df = 0; df < 4; df++) {
      const u16* a = vbase + ((df * 16 + l15) << 10) + t0 + g * 8;
      asm volatile("global_load_dwordx4 %0, %1, off" : "=v"(dst[df]) : "v"(a));
    }
  };

  f32x4 zero = {0.f, 0.f, 0.f, 0.f};
  f32x4 cacc[2][4];
  #pragma unroll
  for (int a = 0; a < 2; a++)
    #pragma unroll
    for (int b = 0; b < 4; b++) cacc[a][b] = zero;
  float rsum[2] = {0.f, 0.f};

  u32x4 kA[6], kB[6], vA[4], vB[4];

  auto chunk = [&](auto LASTC, int c,
                   u32x4 (&curK)[6], u32x4 (&curV)[4],
                   u32x4 (&nxtK)[6], u32x4 (&nxtV)[4]) {
    constexpr bool LAST = decltype(LASTC)::value;
    if constexpr (!LAST) {
      loadK(c + 1, nxtK);
      loadV(c + 1, nxtV);
      asm volatile("s_waitcnt vmcnt(14)" ::: "memory");   // K(c) landed
    } else {
      asm volatile("s_waitcnt vmcnt(4)" ::: "memory");
    }
    __builtin_amdgcn_sched_barrier(0);

    // phase A: S^T = K @ Q^T (K frags in registers)
    __builtin_amdgcn_s_setprio(1);
    f32x4 sacc[2][2];
    sacc[0][0] = zero; sacc[0][1] = zero; sacc[1][0] = zero; sacc[1][1] = zero;
    #pragma unroll
    for (int tf = 0; tf < 2; tf++)
      #pragma unroll
      for (int ks = 0; ks < 3; ks++) {
        s16x8 ak = __builtin_bit_cast(s16x8, curK[tf * 3 + ks]);
        s16x8 b0 = __builtin_bit_cast(s16x8, bqv[0][ks]);
        s16x8 b1 = __builtin_bit_cast(s16x8, bqv[1][ks]);
        sacc[tf][0] = __builtin_amdgcn_mfma_f32_16x16x32_bf16(ak, b0, sacc[tf][0], 0, 0, 0);
        sacc[tf][1] = __builtin_amdgcn_mfma_f32_16x16x32_bf16(ak, b1, sacc[tf][1], 0, 0, 0);
      }
    __builtin_amdgcn_s_setprio(0);

    if constexpr (!LAST) asm volatile("s_waitcnt vmcnt(10)" ::: "memory");  // V(c) landed
    else                 asm volatile("s_waitcnt vmcnt(0)" ::: "memory");
    __builtin_amdgcn_sched_barrier(0);

    // exp2 + pack (beta from LDS; lane holds P[t=tf*16+g*4+j][q=qf*16+l15])
    #pragma unroll
    for (int tf = 0; tf < 2; tf++) {
      f32x4 bb = *(const f32x4*)((const char*)Blds + c * 128 + tf * 64 + g * 16);
      #pragma unroll
      for (int qf = 0; qf < 2; qf++) {
        float e0, e1, e2, e3;
        asm("v_exp_f32 %0, %1" : "=v"(e0) : "v"(sacc[tf][qf][0] + bb[0]));
        asm("v_exp_f32 %0, %1" : "=v"(e1) : "v"(sacc[tf][qf][1] + bb[1]));
        asm("v_exp_f32 %0, %1" : "=v"(e2) : "v"(sacc[tf][qf][2] + bb[2]));
        asm("v_exp_f32 %0, %1" : "=v"(e3) : "v"(sacc[tf][qf][3] + bb[3]));
        rsum[qf] += (e0 + e1) + (e2 + e3);
        u32 p01, p23;
        asm("v_cvt_pk_bf16_f32 %0, %1, %2" : "=v"(p01) : "v"(e0), "v"(e1));
        asm("v_cvt_pk_bf16_f32 %0, %1, %2" : "=v"(p23) : "v"(e2), "v"(e3));
        u32x2 pk = {p01, p23};
        *(u32x2*)(Pw + (qf * 16 + l15) * 80 + tf * 32 + g * 8) = pk;
      }
    }

    // phase B: ctx += P @ V (A = own P from LDS, B = V frags in registers)
    __builtin_amdgcn_s_setprio(1);
    #pragma unroll
    for (int qf = 0; qf < 2; qf++) {
      s16x8 ap = *(const s16x8*)(Pw + (qf * 16 + l15) * 80 + g * 16);
      #pragma unroll
      for (int df = 0; df < 4; df++) {
        s16x8 bv = __builtin_bit_cast(s16x8, curV[df]);
        cacc[qf][df] = __builtin_amdgcn_mfma_f32_16x16x32_bf16(ap, bv, cacc[qf][df], 0, 0, 0);
      }
    }
    __builtin_amdgcn_s_setprio(0);
  };

  loadK(0, kA);
  loadV(0, vA);

  std::integral_constant<bool, false> F;
  std::integral_constant<bool, true>  T;
  #pragma unroll 1
  for (int c2 = 0; c2 < 15; c2++) {
    chunk(F, 2 * c2,     kA, vA, kB, vB);
    chunk(F, 2 * c2 + 1, kB, vB, kA, vA);
  }
  chunk(F, 30, kA, vA, kB, vB);
  chunk(T, 31, kB, vB, kA, vA);

  // epilogue: per-wave softmax normalize + write
  #pragma unroll
  for (int qf = 0; qf < 2; qf++) {
    rsum[qf] += __shfl_xor(rsum[qf], 16);
    rsum[qf] += __shfl_xor(rsum[qf], 32);
  }
  const int b_ = bh / 12, h = bh % 12;
  #pragma unroll
  for (int qf = 0; qf < 2; qf++) {
    #pragma unroll
    for (int j = 0; j < 4; j++) {
      float rs = __shfl(rsum[qf], g * 4 + j);
      float rinv = 1.0f / rs;
      int qg = q0 + qf * 16 + g * 4 + j;
      long base = ((long)(b_ * 1024 + qg)) * 768 + h * 64;
      #pragma unroll
      for (int df = 0; df < 4; df++)
        ctxb[base + df * 16 + l15] = f2bf(cacc[qf][df][j] * rinv);
    }
  }
}

// ---------------- launcher ----------------
extern "C" void kernel_launch(void* const* d_in, const int* in_sizes, int n_in,
                              void* d_out, int out_size, void* d_ws, size_t ws_size,
                              hipStream_t stream)
{
  (void)in_sizes; (void)n_in; (void)out_size; (void)ws_size;
  const float* hs   = (const float*)d_in[0];
  const float* mask = (const float*)d_in[1];
  const float* Wq   = (const float*)d_in[2];
  const float* bq   = (const float*)d_in[3];
  const float* Wk   = (const float*)d_in[4];
  const float* bk   = (const float*)d_in[5];
  const float* Wv   = (const float*)d_in[6];
  const float* bv   = (const float*)d_in[7];
  const float* Wo   = (const float*)d_in[8];
  const float* bo   = (const float*)d_in[9];
  const float* Am   = (const float*)d_in[10];
  float* out = (float*)d_out;

  char* p = (char*)d_ws;
  u16* hsb      = (u16*)p;   p += 6291456;
  u16* wqkvb    = (u16*)p;   p += 3538944;
  u16* wob      = (u16*)p;   p += 1179648;
  float* biasqkv= (float*)p; p += 9216;
  u16* Qb       = (u16*)p;   p += 6291456;
  u16* Kb       = (u16*)p;   p += 6291456;
  u16* Vtb      = (u16*)p;   p += 6291456;
  u16* qAeb     = (u16*)p;   p += 12582912;
  u16* kAeb     = (u16*)p;   p += 12582912;
  float* beta2  = (float*)p; p += 196608;
  u16* ctxb     = (u16*)p;   p += 6291456;

  convert_kernel<<<2688, 256, 0, stream>>>(hs, Wq, Wk, Wv, Wo, bq, bk, bv,
                                           hsb, wqkvb, wob, biasqkv);
  gemm_bt<0><<<1152, 256, 0, stream>>>(hsb, wqkvb, biasqkv,
                                       nullptr, Qb, Kb, Vtb);
  qk_ext_kernel<<<384, 256, 0, stream>>>(Qb, Kb, Am, mask, qAeb, kAeb, beta2);
  attn_kernel<<<1536, 64, 0, stream>>>(qAeb, kAeb, Vtb, beta2, ctxb);
  gemm_bt<1><<<384, 256, 0, stream>>>(ctxb, wob, bo, out,
                                      nullptr, nullptr, nullptr);
}

// Round 8
// 118.752 us; speedup vs baseline: 1.0144x; 1.0144x over previous
//
#include <hip/hip_runtime.h>

typedef __attribute__((ext_vector_type(8))) short s16x8;
typedef __attribute__((ext_vector_type(4))) float f32x4;
typedef __attribute__((ext_vector_type(4))) unsigned int u32x4;
typedef __attribute__((ext_vector_type(2))) unsigned int u32x2;
typedef unsigned short u16;
typedef unsigned int u32;
typedef unsigned long long u64;

__device__ __forceinline__ u16 f2bf(float f) {
  u32 u = __float_as_uint(f);
  u32 r = u + 0x7fffu + ((u >> 16) & 1u);
  return (u16)(r >> 16);
}
__device__ __forceinline__ float bf2f(u16 h) {
  return __uint_as_float(((u32)h) << 16);
}

typedef __attribute__((address_space(3))) char lds_char_t;
typedef __attribute__((address_space(1))) const char glb_char_t;
__device__ __forceinline__ void gl2lds16(const void* g, void* l) {
  __builtin_amdgcn_global_load_lds((glb_char_t*)g, (lds_char_t*)l, 16, 0, 0);
}

#define HS_N 3145728   // 4096*768
#define W_N  589824    // 768*768
#define LOG2E 1.44269504f

// ---------------- K0: f32 -> bf16 conversions + bias concat ----------------
__global__ __launch_bounds__(256) void convert_kernel(
    const float* __restrict__ hs, const float* __restrict__ wq, const float* __restrict__ wk,
    const float* __restrict__ wv, const float* __restrict__ wo,
    const float* __restrict__ bq, const float* __restrict__ bk, const float* __restrict__ bv,
    u16* __restrict__ hsb, u16* __restrict__ wqkvb, u16* __restrict__ wob,
    float* __restrict__ biasqkv)
{
  int t = blockIdx.x * 256 + threadIdx.x;
  long i = (long)t * 8;
  const float* src;
  u16* dst;
  if (i < HS_N)              { src = hs + i;                  dst = hsb + i; }
  else if (i < HS_N + W_N)   { src = wq + (i - HS_N);         dst = wqkvb + (i - HS_N); }
  else if (i < HS_N + 2*W_N) { src = wk + (i - HS_N - W_N);   dst = wqkvb + (i - HS_N); }
  else if (i < HS_N + 3*W_N) { src = wv + (i - HS_N - 2*W_N); dst = wqkvb + (i - HS_N); }
  else                       { src = wo + (i - HS_N - 3*W_N); dst = wob + (i - HS_N - 3*W_N); }
  float4 a = ((const float4*)src)[0];
  float4 b = ((const float4*)src)[1];
  uint4 o;
  o.x = (u32)f2bf(a.x) | ((u32)f2bf(a.y) << 16);
  o.y = (u32)f2bf(a.z) | ((u32)f2bf(a.w) << 16);
  o.z = (u32)f2bf(b.x) | ((u32)f2bf(b.y) << 16);
  o.w = (u32)f2bf(b.z) | ((u32)f2bf(b.w) << 16);
  *(uint4*)dst = o;
  if (t < 2304) biasqkv[t] = (t < 768) ? bq[t] : ((t < 1536) ? bk[t - 768] : bv[t - 1536]);
}

// ---------------- GEMM v2 (unchanged from R4): async-pipelined, C = A @ Bt^T + bias ----
template<int MODE>
__global__ __launch_bounds__(256, 2) void gemm_bt(
    const u16* __restrict__ A, const u16* __restrict__ Bt, const float* __restrict__ bias,
    float* __restrict__ outF, u16* __restrict__ Qb, u16* __restrict__ Kb, u16* __restrict__ Vtb)
{
  constexpr int NT = (MODE == 0) ? 18 : 6;
  constexpr int CPX = NT * 64 / 8;

  __shared__ __align__(16) char sm[73728];
  char* const smA = sm;
  char* const smB = sm + 24576;

  const int tid = threadIdx.x;
  const int lane = tid & 63;
  const int w = tid >> 6;
  const int l15 = lane & 15, g = lane >> 4;
  const int wid = (blockIdx.x & 7) * CPX + (blockIdx.x >> 3);
  const int bx = wid % NT, by = wid / NT;
  const int mBase = by * 64;
  const int nBase = bx * 128;
  const int wr = w >> 1, wc = w & 1;
  const int mW = wr * 32, nW = wc * 64;

  f32x4 zero = {0.f, 0.f, 0.f, 0.f};
  f32x4 acc[2][4];
  #pragma unroll
  for (int i = 0; i < 2; i++)
    #pragma unroll
    for (int j = 0; j < 4; j++) acc[i][j] = zero;

  const u16* Arow = A + (long)mBase * 768;
  const u16* Brow = Bt + (long)nBase * 768;

  auto stage = [&](int c, int kb) {
    const int k0 = c * 64;
    #pragma unroll
    for (int i = 0; i < 2; i++) {
      int o = (i * 256 + tid) * 16;
      int r = o >> 7;
      int sl = ((o >> 4) & 7) ^ (r & 7);
      gl2lds16(Arow + (long)r * 768 + k0 + sl * 8,
               smA + kb * 8192 + i * 4096 + w * 1024);
    }
    #pragma unroll
    for (int i = 0; i < 4; i++) {
      int o = (i * 256 + tid) * 16;
      int r = o >> 7;
      int sl = ((o >> 4) & 7) ^ (r & 7);
      gl2lds16(Brow + (long)r * 768 + k0 + sl * 8,
               smB + kb * 16384 + i * 4096 + w * 1024);
    }
  };

  auto compute = [&](int kb) {
    const char* bufA = smA + kb * 8192;
    const char* bufB = smB + kb * 16384;
    #pragma unroll
    for (int kh = 0; kh < 2; kh++) {
      s16x8 af[2], bf[4];
      #pragma unroll
      for (int mi = 0; mi < 2; mi++) {
        int R = mW + mi * 16 + l15;
        af[mi] = *(const s16x8*)(bufA + R * 128 + (((kh * 4 + g) ^ (l15 & 7)) << 4));
      }
      #pragma unroll
      for (int ni = 0; ni < 4; ni++) {
        int R = nW + ni * 16 + l15;
        bf[ni] = *(const s16x8*)(bufB + R * 128 + (((kh * 4 + g) ^ (l15 & 7)) << 4));
      }
      #pragma unroll
      for (int mi = 0; mi < 2; mi++)
        #pragma unroll
        for (int ni = 0; ni < 4; ni++)
          acc[mi][ni] = __builtin_amdgcn_mfma_f32_16x16x32_bf16(af[mi], bf[ni], acc[mi][ni], 0, 0, 0);
    }
  };

  auto body = [&](int c, int kb, int kbn) {
    if (c < 11) { stage(c + 1, kbn); asm volatile("s_waitcnt vmcnt(6)" ::: "memory"); }
    else        { asm volatile("s_waitcnt vmcnt(0)" ::: "memory"); }
    asm volatile("s_barrier" ::: "memory");
    compute(kb);
  };

  stage(0, 0);
  #pragma unroll 1
  for (int cc = 0; cc < 4; cc++) {
    body(cc * 3,     0, 1);
    body(cc * 3 + 1, 1, 2);
    body(cc * 3 + 2, 2, 0);
  }
  __syncthreads();

  const int b_ = mBase >> 10;
  const int s0b = mBase & 1023;

  if constexpr (MODE == 1) {
    #pragma unroll
    for (int mi = 0; mi < 2; mi++)
      #pragma unroll
      for (int ni = 0; ni < 4; ni++) {
        int n = nBase + nW + ni * 16 + l15;
        int m0 = mBase + mW + mi * 16 + g * 4;
        float bb = bias[n];
        outF[(long)m0 * 768 + n]       = acc[mi][ni][0] + bb;
        outF[(long)(m0 + 1) * 768 + n] = acc[mi][ni][1] + bb;
        outF[(long)(m0 + 2) * 768 + n] = acc[mi][ni][2] + bb;
        outF[(long)(m0 + 3) * 768 + n] = acc[mi][ni][3] + bb;
      }
  } else {
    const int typ = bx / 6;
    if (typ < 2) {
      u16* qk = (typ == 0) ? Qb : Kb;
      #pragma unroll
      for (int mi = 0; mi < 2; mi++)
        #pragma unroll
        for (int ni = 0; ni < 4; ni++) {
          int n = nBase + nW + ni * 16 + l15;
          int hn = n - typ * 768;
          int h = hn >> 6, d = hn & 63;
          long bh = (long)b_ * 12 + h;
          int s0 = s0b + mW + mi * 16 + g * 4;
          float bb = bias[n];
          u16* dst = qk + (bh << 16) + ((long)s0 << 6) + d;
          dst[0]   = f2bf(acc[mi][ni][0] + bb);
          dst[64]  = f2bf(acc[mi][ni][1] + bb);
          dst[128] = f2bf(acc[mi][ni][2] + bb);
          dst[192] = f2bf(acc[mi][ni][3] + bb);
        }
    } else {
      u16* ct = (u16*)sm;
      #pragma unroll
      for (int mi = 0; mi < 2; mi++)
        #pragma unroll
        for (int ni = 0; ni < 4; ni++) {
          int nr = nW + ni * 16 + l15;
          int mr = mW + mi * 16 + g * 4;
          float bb = bias[nBase + nr];
          u32 lo = (u32)f2bf(acc[mi][ni][0] + bb) | ((u32)f2bf(acc[mi][ni][1] + bb) << 16);
          u32 hi = (u32)f2bf(acc[mi][ni][2] + bb) | ((u32)f2bf(acc[mi][ni][3] + bb) << 16);
          *(u64*)(ct + nr * 72 + mr) = (u64)lo | ((u64)hi << 32);
        }
      __syncthreads();
      int dr = tid >> 1, part = tid & 1;
      int hn = (bx - 12) * 128 + dr;
      int h = hn >> 6, d = hn & 63;
      long bh = (long)b_ * 12 + h;
      u16* dst = Vtb + (bh << 16) + (d << 10) + s0b + part * 32;
      const u16* srl = ct + dr * 72 + part * 32;
      #pragma unroll
      for (int i = 0; i < 4; i++)
        *(uint4*)(dst + i * 8) = *(const uint4*)(srl + i * 8);
    }
  }
}

// ---------------- K2 (unchanged from R6): extended features + beta, LOG2E folded -------
// qAe[0:16)=0.25*log2e*qA, [16:80)=0.25e-3*log2e*q, [80:128)=0
// kAe[0:16)=kA, [16:80)=1e-3*k, [80:128)=0
// beta[t] = log2e * (-0.125*(|kA|^2 + 1e-6|k|^2) + mask)
__global__ __launch_bounds__(256) void qk_ext_kernel(
    const u16* __restrict__ Qb, const u16* __restrict__ Kb, const float* __restrict__ Am,
    const float* __restrict__ mask, u16* __restrict__ qAe, u16* __restrict__ kAe,
    float* __restrict__ beta2)
{
  const bool isK = blockIdx.x >= 192;
  const int rb = blockIdx.x * 256 - (isK ? 49152 : 0);
  const int h = (rb >> 10) % 12;
  const int row = rb + threadIdx.x;
  const int bh = row >> 10;
  const int s = row & 1023;
  const int b_ = bh / 12;

  const u16* src = (isK ? Kb : Qb) + ((long)row << 6);
  union { uint4 v4[8]; u32 u[32]; } c;
  #pragma unroll
  for (int i = 0; i < 8; i++) c.v4[i] = ((const uint4*)src)[i];

  const float* Ah = Am + h * 1024;
  float acc[16];
  #pragma unroll
  for (int r = 0; r < 16; r++) acc[r] = 0.f;
  float s2 = 0.f;
  #pragma unroll
  for (int d = 0; d < 64; d++) {
    u32 wd = c.u[d >> 1];
    float qd = bf2f((u16)((d & 1) ? (wd >> 16) : (wd & 0xffffu)));
    s2 += qd * qd;
    #pragma unroll
    for (int r = 0; r < 16; r++) acc[r] += qd * Ah[d * 16 + r];
  }

  union { u16 us[128]; uint4 v4[16]; } o;
  const float sA = isK ? 1.0f : 0.25f * LOG2E;
  const float sQ = isK ? 1e-3f : 0.25e-3f * LOG2E;
  #pragma unroll
  for (int r = 0; r < 16; r++) o.us[r] = f2bf(acc[r] * sA);
  #pragma unroll
  for (int d = 0; d < 64; d++) {
    u32 wd = c.u[d >> 1];
    float qd = bf2f((u16)((d & 1) ? (wd >> 16) : (wd & 0xffffu)));
    o.us[16 + d] = f2bf(qd * sQ);
  }
  #pragma unroll
  for (int j = 80; j < 128; j++) o.us[j] = 0;

  u16* dst = (isK ? kAe : qAe) + ((long)row << 7);
  #pragma unroll
  for (int i = 0; i < 16; i++) ((uint4*)dst)[i] = o.v4[i];

  if (isK) {
    float kk = 1e-6f * s2;
    #pragma unroll
    for (int r = 0; r < 16; r++) kk += acc[r] * acc[r];
    beta2[row] = LOG2E * (-0.125f * kk + mask[(b_ << 10) + s]);
  }
}

// ---------------- K3: attention v6 — R4 structure, 4-wave q-split ----------------
// grid 768 = 48 bh x 16 qtiles(64 rows), XCD-swizzled; block 256 = 4 waves.
// Wave w owns 16 q rows (q0 = qt*64 + w*16), full t-loop (32 chunks of 32).
// K chunk (32x256B) staged to shared LDS dbuf via global_load_lds, 2 instrs/wave,
// XOR-swizzled both-sides (R4-proven). V(4)/beta(2) reg-prefetched per wave.
// Per-wave FIFO/chunk = 8; top vmcnt(6) [K landed], post-A vmcnt(8) [V,B landed];
// never 0 until last chunk. 1 s_barrier/chunk. No cross-wave reduce (q-split).
__global__ __launch_bounds__(256, 3) void attn_kernel(
    const u16* __restrict__ qAe, const u16* __restrict__ kAe, const u16* __restrict__ Vtb,
    const float* __restrict__ beta2, u16* __restrict__ ctxb)
{
  const int tid = threadIdx.x;
  const int lane = tid & 63;
  const int w = tid >> 6;
  const int l15 = lane & 15, g = lane >> 4;
  const int wid = ((int)blockIdx.x & 7) * 96 + ((int)blockIdx.x >> 3);  // 768 = 8*96
  const int bh = wid >> 4;
  const int qt = wid & 15;
  const int q0 = qt * 64 + w * 16;

  __shared__ __align__(16) char sm[16384 + 4 * 1280];
  char* const kb0 = sm;                       // K buf0: 32 rows x 256B, swizzled
  char* const kb1 = sm + 8192;                // K buf1
  char* const Pw  = sm + 16384 + w * 1280;    // per-wave P: 16 rows x 64B (stride 80)

  const u16* qbase = qAe + ((long)(bh * 1024 + q0) << 7);
  const u16* kbase = kAe + ((long)bh << 17);
  const u16* vbase = Vtb + ((long)bh << 16);
  const float* betab = beta2 + (bh << 10);

  // bq fragments for the wave's 16 q-rows (ks=0..2; cols 96..127 zero): 3 VMEM
  u32x4 bqv[3];
  #pragma unroll
  for (int ks = 0; ks < 3; ks++) {
    const u16* a = qbase + (l15 << 7) + ks * 32 + g * 8;
    asm volatile("global_load_dwordx4 %0, %1, off" : "=v"(bqv[ks]) : "v"(a));
  }

  // stage K chunk c: wave w covers instrs i = w*2..w*2+1 (rows i*4..i*4+3 each)
  auto stageK = [&](int c, char* buf) {
    const int t0 = c * 32;
    #pragma unroll
    for (int i2 = 0; i2 < 2; i2++) {
      int i = w * 2 + i2;
      int r = i * 4 + (lane >> 4);
      int col = ((lane & 15) ^ (r & 7)) * 8;          // pre-swizzled source (rule #21)
      gl2lds16(kbase + (long)(t0 + r) * 128 + col, buf + i * 1024);
    }
  };
  auto loadV = [&](int c, u32x4 (&dst)[4]) {
    const int t0 = c * 32;
    #pragma unroll
    for (int df = 0; df < 4; df++) {
      const u16* a = vbase + ((df * 16 + l15) << 10) + t0 + g * 8;
      asm volatile("global_load_dwordx4 %0, %1, off" : "=v"(dst[df]) : "v"(a));
    }
  };
  auto loadB = [&](int c, u32x4 (&dst)[2]) {
    #pragma unroll
    for (int tf = 0; tf < 2; tf++) {
      const float* a = betab + c * 32 + tf * 16 + g * 4;
      asm volatile("global_load_dwordx4 %0, %1, off" : "=v"(dst[tf]) : "v"(a));
    }
  };

  f32x4 zero = {0.f, 0.f, 0.f, 0.f};
  f32x4 cacc[4];
  #pragma unroll
  for (int b = 0; b < 4; b++) cacc[b] = zero;
  float rsum = 0.f;

  u32x4 vA[4], vB[4], bA[2], bB[2];

  // chunk: top vmcnt(6) drains this chunk's K (6 = V+B remaining); barrier;
  // issue next chunk's 8; phase A; vmcnt(8) drains this chunk's V+B; softmax; PV.
  auto chunk = [&](auto LASTC, int c, char* bufc, char* bufn,
                   u32x4 (&curV)[4], u32x4 (&curB)[2],
                   u32x4 (&nxtV)[4], u32x4 (&nxtB)[2]) {
    constexpr bool LAST = decltype(LASTC)::value;
    asm volatile("s_waitcnt vmcnt(6)" ::: "memory");
    asm volatile("s_barrier" ::: "memory");
    if constexpr (!LAST) {
      stageK(c + 1, bufn);
      __builtin_amdgcn_sched_barrier(0);    // keep K oldest in the FIFO
      loadV(c + 1, nxtV);
      loadB(c + 1, nxtB);
    }
    // phase A: S^T = K @ Q^T (K from shared LDS, swizzled read)
    f32x4 sacc[2];
    sacc[0] = zero; sacc[1] = zero;
    #pragma unroll
    for (int tf = 0; tf < 2; tf++)
      #pragma unroll
      for (int ks = 0; ks < 3; ks++) {
        s16x8 ak = *(const s16x8*)(bufc + (tf * 16 + l15) * 256 +
                                   ((ks * 64 + g * 16) ^ ((l15 & 7) << 4)));
        s16x8 bq = __builtin_bit_cast(s16x8, bqv[ks]);
        sacc[tf] = __builtin_amdgcn_mfma_f32_16x16x32_bf16(ak, bq, sacc[tf], 0, 0, 0);
      }
    if constexpr (!LAST) asm volatile("s_waitcnt vmcnt(8)" ::: "memory");
    else                 asm volatile("s_waitcnt vmcnt(0)" ::: "memory");
    __builtin_amdgcn_sched_barrier(0);      // rule #18: pin uses after the wait
    // softmax: P = 2^(S + beta); pack to bf16; P[q=l15][t] at Pw + l15*80 + 2t
    #pragma unroll
    for (int tf = 0; tf < 2; tf++) {
      f32x4 bb = __builtin_bit_cast(f32x4, curB[tf]);
      float e0, e1, e2, e3;
      asm("v_exp_f32 %0, %1" : "=v"(e0) : "v"(sacc[tf][0] + bb[0]));
      asm("v_exp_f32 %0, %1" : "=v"(e1) : "v"(sacc[tf][1] + bb[1]));
      asm("v_exp_f32 %0, %1" : "=v"(e2) : "v"(sacc[tf][2] + bb[2]));
      asm("v_exp_f32 %0, %1" : "=v"(e3) : "v"(sacc[tf][3] + bb[3]));
      rsum += (e0 + e1) + (e2 + e3);
      u32 p01, p23;
      asm("v_cvt_pk_bf16_f32 %0, %1, %2" : "=v"(p01) : "v"(e0), "v"(e1));
      asm("v_cvt_pk_bf16_f32 %0, %1, %2" : "=v"(p23) : "v"(e2), "v"(e3));
      u32x2 pk = {p01, p23};
      *(u32x2*)(Pw + l15 * 80 + tf * 32 + g * 8) = pk;
    }
    // phase B: ctx += P @ V (own-wave P from LDS, V in regs)
    s16x8 ap = *(const s16x8*)(Pw + l15 * 80 + g * 16);
    #pragma unroll
    for (int df = 0; df < 4; df++) {
      s16x8 bv = __builtin_bit_cast(s16x8, curV[df]);
      cacc[df] = __builtin_amdgcn_mfma_f32_16x16x32_bf16(ap, bv, cacc[df], 0, 0, 0);
    }
  };

  // prologue FIFO: [bqv x3][K0 x2][V0 x4][B0 x2] = 11 outstanding
  stageK(0, kb0);
  __builtin_amdgcn_sched_barrier(0);
  loadV(0, vA);
  loadB(0, bA);

  std::integral_constant<bool, false> F;
  std::integral_constant<bool, true>  T;
  #pragma unroll 1
  for (int c2 = 0; c2 < 15; c2++) {
    chunk(F, 2 * c2,     kb0, kb1, vA, bA, vB, bB);
    chunk(F, 2 * c2 + 1, kb1, kb0, vB, bB, vA, bA);
  }
  chunk(F, 30, kb0, kb1, vA, bA, vB, bB);
  chunk(T, 31, kb1, kb0, vB, bB, vA, bA);

  // epilogue: per-wave softmax normalize + write (16 rows, no cross-wave reduce)
  rsum += __shfl_xor(rsum, 16);
  rsum += __shfl_xor(rsum, 32);
  const int b_ = bh / 12, h = bh % 12;
  #pragma unroll
  for (int j = 0; j < 4; j++) {
    float rs = __shfl(rsum, g * 4 + j);
    float rinv = 1.0f / rs;
    int qg = q0 + g * 4 + j;
    long base = ((long)(b_ * 1024 + qg)) * 768 + h * 64;
    #pragma unroll
    for (int df = 0; df < 4; df++)
      ctxb[base + df * 16 + l15] = f2bf(cacc[df][j] * rinv);
  }
}

// ---------------- launcher ----------------
extern "C" void kernel_launch(void* const* d_in, const int* in_sizes, int n_in,
                              void* d_out, int out_size, void* d_ws, size_t ws_size,
                              hipStream_t stream)
{
  (void)in_sizes; (void)n_in; (void)out_size; (void)ws_size;
  const float* hs   = (const float*)d_in[0];
  const float* mask = (const float*)d_in[1];
  const float* Wq   = (const float*)d_in[2];
  const float* bq   = (const float*)d_in[3];
  const float* Wk   = (const float*)d_in[4];
  const float* bk   = (const float*)d_in[5];
  const float* Wv   = (const float*)d_in[6];
  const float* bv   = (const float*)d_in[7];
  const float* Wo   = (const float*)d_in[8];
  const float* bo   = (const float*)d_in[9];
  const float* Am   = (const float*)d_in[10];
  float* out = (float*)d_out;

  char* p = (char*)d_ws;
  u16* hsb      = (u16*)p;   p += 6291456;
  u16* wqkvb    = (u16*)p;   p += 3538944;
  u16* wob      = (u16*)p;   p += 1179648;
  float* biasqkv= (float*)p; p += 9216;
  u16* Qb       = (u16*)p;   p += 6291456;
  u16* Kb       = (u16*)p;   p += 6291456;
  u16* Vtb      = (u16*)p;   p += 6291456;
  u16* qAeb     = (u16*)p;   p += 12582912;
  u16* kAeb     = (u16*)p;   p += 12582912;
  float* beta2  = (float*)p; p += 196608;
  u16* ctxb     = (u16*)p;   p += 6291456;

  convert_kernel<<<2688, 256, 0, stream>>>(hs, Wq, Wk, Wv, Wo, bq, bk, bv,
                                           hsb, wqkvb, wob, biasqkv);
  gemm_bt<0><<<1152, 256, 0, stream>>>(hsb, wqkvb, biasqkv,
                                       nullptr, Qb, Kb, Vtb);
  qk_ext_kernel<<<384, 256, 0, stream>>>(Qb, Kb, Am, mask, qAeb, kAeb, beta2);
  attn_kernel<<<768, 256, 0, stream>>>(qAeb, kAeb, Vtb, beta2, ctxb);
  gemm_bt<1><<<384, 256, 0, stream>>>(ctxb, wob, bo, out,
                                      nullptr, nullptr, nullptr);
}

// Round 9
// 111.728 us; speedup vs baseline: 1.0781x; 1.0629x over previous
//
#include <hip/hip_runtime.h>

typedef __attribute__((ext_vector_type(8))) short s16x8;
typedef __attribute__((ext_vector_type(4))) float f32x4;
typedef __attribute__((ext_vector_type(4))) unsigned int u32x4;
typedef __attribute__((ext_vector_type(2))) unsigned int u32x2;
typedef unsigned short u16;
typedef unsigned int u32;
typedef unsigned long long u64;

__device__ __forceinline__ u16 f2bf(float f) {
  u32 u = __float_as_uint(f);
  u32 r = u + 0x7fffu + ((u >> 16) & 1u);
  return (u16)(r >> 16);
}
__device__ __forceinline__ float bf2f(u16 h) {
  return __uint_as_float(((u32)h) << 16);
}

typedef __attribute__((address_space(3))) char lds_char_t;
typedef __attribute__((address_space(1))) const char glb_char_t;
__device__ __forceinline__ void gl2lds16(const void* g, void* l) {
  __builtin_amdgcn_global_load_lds((glb_char_t*)g, (lds_char_t*)l, 16, 0, 0);
}

#define HS_N 3145728   // 4096*768
#define W_N  589824    // 768*768
#define LOG2E 1.44269504f

// ---------------- K0: f32 -> bf16 conversions + bias concat ----------------
__global__ __launch_bounds__(256) void convert_kernel(
    const float* __restrict__ hs, const float* __restrict__ wq, const float* __restrict__ wk,
    const float* __restrict__ wv, const float* __restrict__ wo,
    const float* __restrict__ bq, const float* __restrict__ bk, const float* __restrict__ bv,
    u16* __restrict__ hsb, u16* __restrict__ wqkvb, u16* __restrict__ wob,
    float* __restrict__ biasqkv)
{
  int t = blockIdx.x * 256 + threadIdx.x;
  long i = (long)t * 8;
  const float* src;
  u16* dst;
  if (i < HS_N)              { src = hs + i;                  dst = hsb + i; }
  else if (i < HS_N + W_N)   { src = wq + (i - HS_N);         dst = wqkvb + (i - HS_N); }
  else if (i < HS_N + 2*W_N) { src = wk + (i - HS_N - W_N);   dst = wqkvb + (i - HS_N); }
  else if (i < HS_N + 3*W_N) { src = wv + (i - HS_N - 2*W_N); dst = wqkvb + (i - HS_N); }
  else                       { src = wo + (i - HS_N - 3*W_N); dst = wob + (i - HS_N - 3*W_N); }
  float4 a = ((const float4*)src)[0];
  float4 b = ((const float4*)src)[1];
  uint4 o;
  o.x = (u32)f2bf(a.x) | ((u32)f2bf(a.y) << 16);
  o.y = (u32)f2bf(a.z) | ((u32)f2bf(a.w) << 16);
  o.z = (u32)f2bf(b.x) | ((u32)f2bf(b.y) << 16);
  o.w = (u32)f2bf(b.z) | ((u32)f2bf(b.w) << 16);
  *(uint4*)dst = o;
  if (t < 2304) biasqkv[t] = (t < 768) ? bq[t] : ((t < 1536) ? bk[t - 768] : bv[t - 1536]);
}

// ---------------- GEMM v2 (unchanged from R4): async-pipelined, C = A @ Bt^T + bias ----
template<int MODE>
__global__ __launch_bounds__(256, 2) void gemm_bt(
    const u16* __restrict__ A, const u16* __restrict__ Bt, const float* __restrict__ bias,
    float* __restrict__ outF, u16* __restrict__ Qb, u16* __restrict__ Kb, u16* __restrict__ Vtb)
{
  constexpr int NT = (MODE == 0) ? 18 : 6;
  constexpr int CPX = NT * 64 / 8;

  __shared__ __align__(16) char sm[73728];
  char* const smA = sm;
  char* const smB = sm + 24576;

  const int tid = threadIdx.x;
  const int lane = tid & 63;
  const int w = tid >> 6;
  const int l15 = lane & 15, g = lane >> 4;
  const int wid = (blockIdx.x & 7) * CPX + (blockIdx.x >> 3);
  const int bx = wid % NT, by = wid / NT;
  const int mBase = by * 64;
  const int nBase = bx * 128;
  const int wr = w >> 1, wc = w & 1;
  const int mW = wr * 32, nW = wc * 64;

  f32x4 zero = {0.f, 0.f, 0.f, 0.f};
  f32x4 acc[2][4];
  #pragma unroll
  for (int i = 0; i < 2; i++)
    #pragma unroll
    for (int j = 0; j < 4; j++) acc[i][j] = zero;

  const u16* Arow = A + (long)mBase * 768;
  const u16* Brow = Bt + (long)nBase * 768;

  auto stage = [&](int c, int kb) {
    const int k0 = c * 64;
    #pragma unroll
    for (int i = 0; i < 2; i++) {
      int o = (i * 256 + tid) * 16;
      int r = o >> 7;
      int sl = ((o >> 4) & 7) ^ (r & 7);
      gl2lds16(Arow + (long)r * 768 + k0 + sl * 8,
               smA + kb * 8192 + i * 4096 + w * 1024);
    }
    #pragma unroll
    for (int i = 0; i < 4; i++) {
      int o = (i * 256 + tid) * 16;
      int r = o >> 7;
      int sl = ((o >> 4) & 7) ^ (r & 7);
      gl2lds16(Brow + (long)r * 768 + k0 + sl * 8,
               smB + kb * 16384 + i * 4096 + w * 1024);
    }
  };

  auto compute = [&](int kb) {
    const char* bufA = smA + kb * 8192;
    const char* bufB = smB + kb * 16384;
    #pragma unroll
    for (int kh = 0; kh < 2; kh++) {
      s16x8 af[2], bf[4];
      #pragma unroll
      for (int mi = 0; mi < 2; mi++) {
        int R = mW + mi * 16 + l15;
        af[mi] = *(const s16x8*)(bufA + R * 128 + (((kh * 4 + g) ^ (l15 & 7)) << 4));
      }
      #pragma unroll
      for (int ni = 0; ni < 4; ni++) {
        int R = nW + ni * 16 + l15;
        bf[ni] = *(const s16x8*)(bufB + R * 128 + (((kh * 4 + g) ^ (l15 & 7)) << 4));
      }
      #pragma unroll
      for (int mi = 0; mi < 2; mi++)
        #pragma unroll
        for (int ni = 0; ni < 4; ni++)
          acc[mi][ni] = __builtin_amdgcn_mfma_f32_16x16x32_bf16(af[mi], bf[ni], acc[mi][ni], 0, 0, 0);
    }
  };

  auto body = [&](int c, int kb, int kbn) {
    if (c < 11) { stage(c + 1, kbn); asm volatile("s_waitcnt vmcnt(6)" ::: "memory"); }
    else        { asm volatile("s_waitcnt vmcnt(0)" ::: "memory"); }
    asm volatile("s_barrier" ::: "memory");
    compute(kb);
  };

  stage(0, 0);
  #pragma unroll 1
  for (int cc = 0; cc < 4; cc++) {
    body(cc * 3,     0, 1);
    body(cc * 3 + 1, 1, 2);
    body(cc * 3 + 2, 2, 0);
  }
  __syncthreads();

  const int b_ = mBase >> 10;
  const int s0b = mBase & 1023;

  if constexpr (MODE == 1) {
    #pragma unroll
    for (int mi = 0; mi < 2; mi++)
      #pragma unroll
      for (int ni = 0; ni < 4; ni++) {
        int n = nBase + nW + ni * 16 + l15;
        int m0 = mBase + mW + mi * 16 + g * 4;
        float bb = bias[n];
        outF[(long)m0 * 768 + n]       = acc[mi][ni][0] + bb;
        outF[(long)(m0 + 1) * 768 + n] = acc[mi][ni][1] + bb;
        outF[(long)(m0 + 2) * 768 + n] = acc[mi][ni][2] + bb;
        outF[(long)(m0 + 3) * 768 + n] = acc[mi][ni][3] + bb;
      }
  } else {
    const int typ = bx / 6;
    if (typ < 2) {
      u16* qk = (typ == 0) ? Qb : Kb;
      #pragma unroll
      for (int mi = 0; mi < 2; mi++)
        #pragma unroll
        for (int ni = 0; ni < 4; ni++) {
          int n = nBase + nW + ni * 16 + l15;
          int hn = n - typ * 768;
          int h = hn >> 6, d = hn & 63;
          long bh = (long)b_ * 12 + h;
          int s0 = s0b + mW + mi * 16 + g * 4;
          float bb = bias[n];
          u16* dst = qk + (bh << 16) + ((long)s0 << 6) + d;
          dst[0]   = f2bf(acc[mi][ni][0] + bb);
          dst[64]  = f2bf(acc[mi][ni][1] + bb);
          dst[128] = f2bf(acc[mi][ni][2] + bb);
          dst[192] = f2bf(acc[mi][ni][3] + bb);
        }
    } else {
      u16* ct = (u16*)sm;
      #pragma unroll
      for (int mi = 0; mi < 2; mi++)
        #pragma unroll
        for (int ni = 0; ni < 4; ni++) {
          int nr = nW + ni * 16 + l15;
          int mr = mW + mi * 16 + g * 4;
          float bb = bias[nBase + nr];
          u32 lo = (u32)f2bf(acc[mi][ni][0] + bb) | ((u32)f2bf(acc[mi][ni][1] + bb) << 16);
          u32 hi = (u32)f2bf(acc[mi][ni][2] + bb) | ((u32)f2bf(acc[mi][ni][3] + bb) << 16);
          *(u64*)(ct + nr * 72 + mr) = (u64)lo | ((u64)hi << 32);
        }
      __syncthreads();
      int dr = tid >> 1, part = tid & 1;
      int hn = (bx - 12) * 128 + dr;
      int h = hn >> 6, d = hn & 63;
      long bh = (long)b_ * 12 + h;
      u16* dst = Vtb + (bh << 16) + (d << 10) + s0b + part * 32;
      const u16* srl = ct + dr * 72 + part * 32;
      #pragma unroll
      for (int i = 0; i < 4; i++)
        *(uint4*)(dst + i * 8) = *(const uint4*)(srl + i * 8);
    }
  }
}

// ---------------- K2 (unchanged): extended features + beta, LOG2E folded ----------------
__global__ __launch_bounds__(256) void qk_ext_kernel(
    const u16* __restrict__ Qb, const u16* __restrict__ Kb, const float* __restrict__ Am,
    const float* __restrict__ mask, u16* __restrict__ qAe, u16* __restrict__ kAe,
    float* __restrict__ beta2)
{
  const bool isK = blockIdx.x >= 192;
  const int rb = blockIdx.x * 256 - (isK ? 49152 : 0);
  const int h = (rb >> 10) % 12;
  const int row = rb + threadIdx.x;
  const int bh = row >> 10;
  const int s = row & 1023;
  const int b_ = bh / 12;

  const u16* src = (isK ? Kb : Qb) + ((long)row << 6);
  union { uint4 v4[8]; u32 u[32]; } c;
  #pragma unroll
  for (int i = 0; i < 8; i++) c.v4[i] = ((const uint4*)src)[i];

  const float* Ah = Am + h * 1024;
  float acc[16];
  #pragma unroll
  for (int r = 0; r < 16; r++) acc[r] = 0.f;
  float s2 = 0.f;
  #pragma unroll
  for (int d = 0; d < 64; d++) {
    u32 wd = c.u[d >> 1];
    float qd = bf2f((u16)((d & 1) ? (wd >> 16) : (wd & 0xffffu)));
    s2 += qd * qd;
    #pragma unroll
    for (int r = 0; r < 16; r++) acc[r] += qd * Ah[d * 16 + r];
  }

  union { u16 us[128]; uint4 v4[16]; } o;
  const float sA = isK ? 1.0f : 0.25f * LOG2E;
  const float sQ = isK ? 1e-3f : 0.25e-3f * LOG2E;
  #pragma unroll
  for (int r = 0; r < 16; r++) o.us[r] = f2bf(acc[r] * sA);
  #pragma unroll
  for (int d = 0; d < 64; d++) {
    u32 wd = c.u[d >> 1];
    float qd = bf2f((u16)((d & 1) ? (wd >> 16) : (wd & 0xffffu)));
    o.us[16 + d] = f2bf(qd * sQ);
  }
  #pragma unroll
  for (int j = 80; j < 128; j++) o.us[j] = 0;

  u16* dst = (isK ? kAe : qAe) + ((long)row << 7);
  #pragma unroll
  for (int i = 0; i < 16; i++) ((uint4*)dst)[i] = o.v4[i];

  if (isK) {
    float kk = 1e-6f * s2;
    #pragma unroll
    for (int r = 0; r < 16; r++) kk += acc[r] * acc[r];
    beta2[row] = LOG2E * (-0.125f * kk + mask[(b_ << 10) + s]);
  }
}

// ---------------- K3: attention v7 — depth-2 software pipeline ----------------
// grid 768 = 48 bh x 16 qtiles(64 rows), XCD-swizzled; block 128 = 2 waves,
// wave owns 32 q rows. Per iteration c: exp(c) -> P(c) write -> QK(c+1) MFMAs
// (hide the P LDS round-trip + K ds_read latency) -> P(c) read -> PV(c).
// K tri-buffered via global_load_lds (stage c+2 pre-wait: WAR-safe, that buffer
// was last read two barriers ago). One counted vmcnt(10) + one s_barrier / iter.
__global__ __launch_bounds__(128, 2) void attn_kernel(
    const u16* __restrict__ qAe, const u16* __restrict__ kAe, const u16* __restrict__ Vtb,
    const float* __restrict__ beta2, u16* __restrict__ ctxb)
{
  const int tid = threadIdx.x;
  const int lane = tid & 63;
  const int w = tid >> 6;
  const int l15 = lane & 15, g = lane >> 4;
  const int wid = ((int)blockIdx.x & 7) * 96 + ((int)blockIdx.x >> 3);  // 768 = 8*96
  const int bh = wid >> 4;
  const int qt = wid & 15;
  const int q0 = qt * 64 + w * 32;

  __shared__ __align__(16) char sm[3 * 8192 + 2 * 2560];
  char* const kb0 = sm;
  char* const kb1 = sm + 8192;
  char* const kb2 = sm + 16384;
  char* const Pw  = sm + 24576 + w * 2560;    // per-wave P: 32 rows x 64B (stride 80)

  const u16* qbase = qAe + ((long)(bh * 1024 + q0) << 7);
  const u16* kbase = kAe + ((long)bh << 17);
  const u16* vbase = Vtb + ((long)bh << 16);
  const float* betab = beta2 + (bh << 10);

  // bq fragments (ks=0..2; cols 96..127 zero): 6 VMEM
  u32x4 bqv[2][3];
  #pragma unroll
  for (int qf = 0; qf < 2; qf++)
    #pragma unroll
    for (int ks = 0; ks < 3; ks++) {
      const u16* a = qbase + ((qf * 16 + l15) << 7) + ks * 32 + g * 8;
      asm volatile("global_load_dwordx4 %0, %1, off" : "=v"(bqv[qf][ks]) : "v"(a));
    }

  // stage K chunk c: wave w covers instrs i = w*4..w*4+3 (rows i*4..i*4+3)
  auto stageK = [&](int c, char* buf) {
    const int t0 = c * 32;
    #pragma unroll
    for (int i2 = 0; i2 < 4; i2++) {
      int i = w * 4 + i2;
      int r = i * 4 + (lane >> 4);
      int col = ((lane & 15) ^ (r & 7)) * 8;          // pre-swizzled source (rule #21)
      gl2lds16(kbase + (long)(t0 + r) * 128 + col, buf + i * 1024);
    }
  };
  auto loadV = [&](int c, u32x4 (&dst)[4]) {
    const int t0 = c * 32;
    #pragma unroll
    for (int df = 0; df < 4; df++) {
      const u16* a = vbase + ((df * 16 + l15) << 10) + t0 + g * 8;
      asm volatile("global_load_dwordx4 %0, %1, off" : "=v"(dst[df]) : "v"(a));
    }
  };
  auto loadB = [&](int c, u32x4 (&dst)[2]) {
    #pragma unroll
    for (int tf = 0; tf < 2; tf++) {
      const float* a = betab + c * 32 + tf * 16 + g * 4;
      asm volatile("global_load_dwordx4 %0, %1, off" : "=v"(dst[tf]) : "v"(a));
    }
  };

  f32x4 zero = {0.f, 0.f, 0.f, 0.f};
  f32x4 cacc[2][4];
  #pragma unroll
  for (int a = 0; a < 2; a++)
    #pragma unroll
    for (int b = 0; b < 4; b++) cacc[a][b] = zero;
  float rsum[2] = {0.f, 0.f};

  u32x4 vA[4], vB[4], bA[2], bB[2];
  f32x4 sA[2][2], sB[2][2];

  auto qk = [&](const char* kbuf, f32x4 (&s)[2][2]) {
    s[0][0] = zero; s[0][1] = zero; s[1][0] = zero; s[1][1] = zero;
    #pragma unroll
    for (int tf = 0; tf < 2; tf++)
      #pragma unroll
      for (int ks = 0; ks < 3; ks++) {
        s16x8 ak = *(const s16x8*)(kbuf + (tf * 16 + l15) * 256 +
                                   ((ks * 64 + g * 16) ^ ((l15 & 7) << 4)));
        s16x8 b0 = __builtin_bit_cast(s16x8, bqv[0][ks]);
        s16x8 b1 = __builtin_bit_cast(s16x8, bqv[1][ks]);
        s[tf][0] = __builtin_amdgcn_mfma_f32_16x16x32_bf16(ak, b0, s[tf][0], 0, 0, 0);
        s[tf][1] = __builtin_amdgcn_mfma_f32_16x16x32_bf16(ak, b1, s[tf][1], 0, 0, 0);
      }
  };

  // iter(c): finish chunk c (exp+PV), compute QK(c+1), stage K(c+2).
  auto iter = [&](auto VNC, auto STGC, auto QKC, int c, char* sbuf, const char* kbuf,
                  u32x4 (&vcur)[4], u32x4 (&bcur)[2],
                  u32x4 (&vnxt)[4], u32x4 (&bnxt)[2],
                  f32x4 (&scur)[2][2], f32x4 (&snxt)[2][2]) {
    constexpr int  VN    = decltype(VNC)::value;
    constexpr bool DOSTG = decltype(STGC)::value;
    constexpr bool DOQK  = decltype(QKC)::value;
    if constexpr (DOSTG) {
      stageK(c + 2, sbuf);
      __builtin_amdgcn_sched_barrier(0);        // keep K oldest among this iter's issues
    }
    if constexpr (DOQK) { loadV(c + 1, vnxt); loadB(c + 1, bnxt); }
    if constexpr (VN == 10)     asm volatile("s_waitcnt vmcnt(10)" ::: "memory");
    else if constexpr (VN == 6) asm volatile("s_waitcnt vmcnt(6)"  ::: "memory");
    else                        asm volatile("s_waitcnt vmcnt(0)"  ::: "memory");
    asm volatile("s_barrier" ::: "memory");
    __builtin_amdgcn_sched_barrier(0);          // rule #18: pin all uses after the wait
    // exp(c): P = 2^(S + beta) -> bf16 -> per-wave LDS
    #pragma unroll
    for (int tf = 0; tf < 2; tf++) {
      f32x4 bb = __builtin_bit_cast(f32x4, bcur[tf]);
      #pragma unroll
      for (int qf = 0; qf < 2; qf++) {
        float e0, e1, e2, e3;
        asm("v_exp_f32 %0, %1" : "=v"(e0) : "v"(scur[tf][qf][0] + bb[0]));
        asm("v_exp_f32 %0, %1" : "=v"(e1) : "v"(scur[tf][qf][1] + bb[1]));
        asm("v_exp_f32 %0, %1" : "=v"(e2) : "v"(scur[tf][qf][2] + bb[2]));
        asm("v_exp_f32 %0, %1" : "=v"(e3) : "v"(scur[tf][qf][3] + bb[3]));
        rsum[qf] += (e0 + e1) + (e2 + e3);
        u32 p01, p23;
        asm("v_cvt_pk_bf16_f32 %0, %1, %2" : "=v"(p01) : "v"(e0), "v"(e1));
        asm("v_cvt_pk_bf16_f32 %0, %1, %2" : "=v"(p23) : "v"(e2), "v"(e3));
        u32x2 pk = {p01, p23};
        *(u32x2*)(Pw + (qf * 16 + l15) * 80 + tf * 32 + g * 8) = pk;
      }
    }
    // QK(c+1): 12 MFMA — hides P write->read latency and K ds_read latency
    if constexpr (DOQK) qk(kbuf, snxt);
    // PV(c): read own P, multiply with V regs
    #pragma unroll
    for (int qf = 0; qf < 2; qf++) {
      s16x8 ap = *(const s16x8*)(Pw + (qf * 16 + l15) * 80 + g * 16);
      #pragma unroll
      for (int df = 0; df < 4; df++) {
        s16x8 bv = __builtin_bit_cast(s16x8, vcur[df]);
        cacc[qf][df] = __builtin_amdgcn_mfma_f32_16x16x32_bf16(ap, bv, cacc[qf][df], 0, 0, 0);
      }
    }
  };

  // prologue FIFO: [bqv 6][K0 4][K1 4][V0 4][B0 2]; vmcnt(10) -> bqv+K0 landed
  stageK(0, kb0);
  stageK(1, kb1);
  __builtin_amdgcn_sched_barrier(0);
  loadV(0, vA);
  loadB(0, bA);
  asm volatile("s_waitcnt vmcnt(10)" ::: "memory");
  asm volatile("s_barrier" ::: "memory");
  __builtin_amdgcn_sched_barrier(0);
  qk(kb0, sA);                                   // sacc(0)

  std::integral_constant<int, 10> V10;
  std::integral_constant<int, 6>  V6;
  std::integral_constant<int, 0>  V0;
  std::integral_constant<bool, true>  Tt;
  std::integral_constant<bool, false> Ff;

  #pragma unroll 1
  for (int c6 = 0; c6 < 5; c6++) {
    int c = c6 * 6;
    iter(V10, Tt, Tt, c + 0, kb2, kb1, vA, bA, vB, bB, sA, sB);
    iter(V10, Tt, Tt, c + 1, kb0, kb2, vB, bB, vA, bA, sB, sA);
    iter(V10, Tt, Tt, c + 2, kb1, kb0, vA, bA, vB, bB, sA, sB);
    iter(V10, Tt, Tt, c + 3, kb2, kb1, vB, bB, vA, bA, sB, sA);
    iter(V10, Tt, Tt, c + 4, kb0, kb2, vA, bA, vB, bB, sA, sB);
    iter(V10, Tt, Tt, c + 5, kb1, kb0, vB, bB, vA, bA, sB, sA);
  }
  // c=30: no stage(32); issue V/B(31); drain stage(31)+V(30)+B(30) -> vmcnt(6)
  iter(V6, Ff, Tt, 30, kb0, kb1, vA, bA, vB, bB, sA, sB);
  // c=31: nothing to issue; drain V(31)+B(31) -> vmcnt(0); no QK
  iter(V0, Ff, Ff, 31, kb0, kb0, vB, bB, vA, bA, sB, sA);

  // epilogue: per-wave softmax normalize + write
  #pragma unroll
  for (int qf = 0; qf < 2; qf++) {
    rsum[qf] += __shfl_xor(rsum[qf], 16);
    rsum[qf] += __shfl_xor(rsum[qf], 32);
  }
  const int b_ = bh / 12, h = bh % 12;
  #pragma unroll
  for (int qf = 0; qf < 2; qf++) {
    #pragma unroll
    for (int j = 0; j < 4; j++) {
      float rs = __shfl(rsum[qf], g * 4 + j);
      float rinv = 1.0f / rs;
      int qg = q0 + qf * 16 + g * 4 + j;
      long base = ((long)(b_ * 1024 + qg)) * 768 + h * 64;
      #pragma unroll
      for (int df = 0; df < 4; df++)
        ctxb[base + df * 16 + l15] = f2bf(cacc[qf][df][j] * rinv);
    }
  }
}

// ---------------- launcher ----------------
extern "C" void kernel_launch(void* const* d_in, const int* in_sizes, int n_in,
                              void* d_out, int out_size, void* d_ws, size_t ws_size,
                              hipStream_t stream)
{
  (void)in_sizes; (void)n_in; (void)out_size; (void)ws_size;
  const float* hs   = (const float*)d_in[0];
  const float* mask = (const float*)d_in[1];
  const float* Wq   = (const float*)d_in[2];
  const float* bq   = (const float*)d_in[3];
  const float* Wk   = (const float*)d_in[4];
  const float* bk   = (const float*)d_in[5];
  const float* Wv   = (const float*)d_in[6];
  const float* bv   = (const float*)d_in[7];
  const float* Wo   = (const float*)d_in[8];
  const float* bo   = (const float*)d_in[9];
  const float* Am   = (const float*)d_in[10];
  float* out = (float*)d_out;

  char* p = (char*)d_ws;
  u16* hsb      = (u16*)p;   p += 6291456;
  u16* wqkvb    = (u16*)p;   p += 3538944;
  u16* wob      = (u16*)p;   p += 1179648;
  float* biasqkv= (float*)p; p += 9216;
  u16* Qb       = (u16*)p;   p += 6291456;
  u16* Kb       = (u16*)p;   p += 6291456;
  u16* Vtb      = (u16*)p;   p += 6291456;
  u16* qAeb     = (u16*)p;   p += 12582912;
  u16* kAeb     = (u16*)p;   p += 12582912;
  float* beta2  = (float*)p; p += 196608;
  u16* ctxb     = (u16*)p;   p += 6291456;

  convert_kernel<<<2688, 256, 0, stream>>>(hs, Wq, Wk, Wv, Wo, bq, bk, bv,
                                           hsb, wqkvb, wob, biasqkv);
  gemm_bt<0><<<1152, 256, 0, stream>>>(hsb, wqkvb, biasqkv,
                                       nullptr, Qb, Kb, Vtb);
  qk_ext_kernel<<<384, 256, 0, stream>>>(Qb, Kb, Am, mask, qAeb, kAeb, beta2);
  attn_kernel<<<768, 128, 0, stream>>>(qAeb, kAeb, Vtb, beta2, ctxb);
  gemm_bt<1><<<384, 256, 0, stream>>>(ctxb, wob, bo, out,
                                      nullptr, nullptr, nullptr);
}

// Round 10
// 95.248 us; speedup vs baseline: 1.2647x; 1.1730x over previous
//
#include <hip/hip_runtime.h>

typedef __attribute__((ext_vector_type(8))) short s16x8;
typedef __attribute__((ext_vector_type(4))) float f32x4;
typedef __attribute__((ext_vector_type(4))) unsigned int u32x4;
typedef __attribute__((ext_vector_type(2))) unsigned int u32x2;
typedef unsigned short u16;
typedef unsigned int u32;
typedef unsigned long long u64;

__device__ __forceinline__ u16 f2bf(float f) {
  u32 u = __float_as_uint(f);
  u32 r = u + 0x7fffu + ((u >> 16) & 1u);
  return (u16)(r >> 16);
}
__device__ __forceinline__ float bf2f(u16 h) {
  return __uint_as_float(((u32)h) << 16);
}

typedef __attribute__((address_space(3))) char lds_char_t;
typedef __attribute__((address_space(1))) const char glb_char_t;
__device__ __forceinline__ void gl2lds16(const void* g, void* l) {
  __builtin_amdgcn_global_load_lds((glb_char_t*)g, (lds_char_t*)l, 16, 0, 0);
}

#define HS_N 3145728   // 4096*768
#define W_N  589824    // 768*768
#define LOG2E 1.44269504f

// ---------------- K0: f32 -> bf16 conversions + bias concat ----------------
__global__ __launch_bounds__(256) void convert_kernel(
    const float* __restrict__ hs, const float* __restrict__ wq, const float* __restrict__ wk,
    const float* __restrict__ wv, const float* __restrict__ wo,
    const float* __restrict__ bq, const float* __restrict__ bk, const float* __restrict__ bv,
    u16* __restrict__ hsb, u16* __restrict__ wqkvb, u16* __restrict__ wob,
    float* __restrict__ biasqkv)
{
  int t = blockIdx.x * 256 + threadIdx.x;
  long i = (long)t * 8;
  const float* src;
  u16* dst;
  if (i < HS_N)              { src = hs + i;                  dst = hsb + i; }
  else if (i < HS_N + W_N)   { src = wq + (i - HS_N);         dst = wqkvb + (i - HS_N); }
  else if (i < HS_N + 2*W_N) { src = wk + (i - HS_N - W_N);   dst = wqkvb + (i - HS_N); }
  else if (i < HS_N + 3*W_N) { src = wv + (i - HS_N - 2*W_N); dst = wqkvb + (i - HS_N); }
  else                       { src = wo + (i - HS_N - 3*W_N); dst = wob + (i - HS_N - 3*W_N); }
  float4 a = ((const float4*)src)[0];
  float4 b = ((const float4*)src)[1];
  uint4 o;
  o.x = (u32)f2bf(a.x) | ((u32)f2bf(a.y) << 16);
  o.y = (u32)f2bf(a.z) | ((u32)f2bf(a.w) << 16);
  o.z = (u32)f2bf(b.x) | ((u32)f2bf(b.y) << 16);
  o.w = (u32)f2bf(b.z) | ((u32)f2bf(b.w) << 16);
  *(uint4*)dst = o;
  if (t < 2304) biasqkv[t] = (t < 768) ? bq[t] : ((t < 1536) ? bk[t - 768] : bv[t - 1536]);
}

// ---------------- GEMM v2 (unchanged from R4): async-pipelined, C = A @ Bt^T + bias ----
template<int MODE>
__global__ __launch_bounds__(256, 2) void gemm_bt(
    const u16* __restrict__ A, const u16* __restrict__ Bt, const float* __restrict__ bias,
    float* __restrict__ outF, u16* __restrict__ Qb, u16* __restrict__ Kb, u16* __restrict__ Vtb)
{
  constexpr int NT = (MODE == 0) ? 18 : 6;
  constexpr int CPX = NT * 64 / 8;

  __shared__ __align__(16) char sm[73728];
  char* const smA = sm;
  char* const smB = sm + 24576;

  const int tid = threadIdx.x;
  const int lane = tid & 63;
  const int w = tid >> 6;
  const int l15 = lane & 15, g = lane >> 4;
  const int wid = (blockIdx.x & 7) * CPX + (blockIdx.x >> 3);
  const int bx = wid % NT, by = wid / NT;
  const int mBase = by * 64;
  const int nBase = bx * 128;
  const int wr = w >> 1, wc = w & 1;
  const int mW = wr * 32, nW = wc * 64;

  f32x4 zero = {0.f, 0.f, 0.f, 0.f};
  f32x4 acc[2][4];
  #pragma unroll
  for (int i = 0; i < 2; i++)
    #pragma unroll
    for (int j = 0; j < 4; j++) acc[i][j] = zero;

  const u16* Arow = A + (long)mBase * 768;
  const u16* Brow = Bt + (long)nBase * 768;

  auto stage = [&](int c, int kb) {
    const int k0 = c * 64;
    #pragma unroll
    for (int i = 0; i < 2; i++) {
      int o = (i * 256 + tid) * 16;
      int r = o >> 7;
      int sl = ((o >> 4) & 7) ^ (r & 7);
      gl2lds16(Arow + (long)r * 768 + k0 + sl * 8,
               smA + kb * 8192 + i * 4096 + w * 1024);
    }
    #pragma unroll
    for (int i = 0; i < 4; i++) {
      int o = (i * 256 + tid) * 16;
      int r = o >> 7;
      int sl = ((o >> 4) & 7) ^ (r & 7);
      gl2lds16(Brow + (long)r * 768 + k0 + sl * 8,
               smB + kb * 16384 + i * 4096 + w * 1024);
    }
  };

  auto compute = [&](int kb) {
    const char* bufA = smA + kb * 8192;
    const char* bufB = smB + kb * 16384;
    #pragma unroll
    for (int kh = 0; kh < 2; kh++) {
      s16x8 af[2], bf[4];
      #pragma unroll
      for (int mi = 0; mi < 2; mi++) {
        int R = mW + mi * 16 + l15;
        af[mi] = *(const s16x8*)(bufA + R * 128 + (((kh * 4 + g) ^ (l15 & 7)) << 4));
      }
      #pragma unroll
      for (int ni = 0; ni < 4; ni++) {
        int R = nW + ni * 16 + l15;
        bf[ni] = *(const s16x8*)(bufB + R * 128 + (((kh * 4 + g) ^ (l15 & 7)) << 4));
      }
      #pragma unroll
      for (int mi = 0; mi < 2; mi++)
        #pragma unroll
        for (int ni = 0; ni < 4; ni++)
          acc[mi][ni] = __builtin_amdgcn_mfma_f32_16x16x32_bf16(af[mi], bf[ni], acc[mi][ni], 0, 0, 0);
    }
  };

  auto body = [&](int c, int kb, int kbn) {
    if (c < 11) { stage(c + 1, kbn); asm volatile("s_waitcnt vmcnt(6)" ::: "memory"); }
    else        { asm volatile("s_waitcnt vmcnt(0)" ::: "memory"); }
    asm volatile("s_barrier" ::: "memory");
    compute(kb);
  };

  stage(0, 0);
  #pragma unroll 1
  for (int cc = 0; cc < 4; cc++) {
    body(cc * 3,     0, 1);
    body(cc * 3 + 1, 1, 2);
    body(cc * 3 + 2, 2, 0);
  }
  __syncthreads();

  const int b_ = mBase >> 10;
  const int s0b = mBase & 1023;

  if constexpr (MODE == 1) {
    #pragma unroll
    for (int mi = 0; mi < 2; mi++)
      #pragma unroll
      for (int ni = 0; ni < 4; ni++) {
        int n = nBase + nW + ni * 16 + l15;
        int m0 = mBase + mW + mi * 16 + g * 4;
        float bb = bias[n];
        outF[(long)m0 * 768 + n]       = acc[mi][ni][0] + bb;
        outF[(long)(m0 + 1) * 768 + n] = acc[mi][ni][1] + bb;
        outF[(long)(m0 + 2) * 768 + n] = acc[mi][ni][2] + bb;
        outF[(long)(m0 + 3) * 768 + n] = acc[mi][ni][3] + bb;
      }
  } else {
    const int typ = bx / 6;
    if (typ < 2) {
      u16* qk = (typ == 0) ? Qb : Kb;
      #pragma unroll
      for (int mi = 0; mi < 2; mi++)
        #pragma unroll
        for (int ni = 0; ni < 4; ni++) {
          int n = nBase + nW + ni * 16 + l15;
          int hn = n - typ * 768;
          int h = hn >> 6, d = hn & 63;
          long bh = (long)b_ * 12 + h;
          int s0 = s0b + mW + mi * 16 + g * 4;
          float bb = bias[n];
          u16* dst = qk + (bh << 16) + ((long)s0 << 6) + d;
          dst[0]   = f2bf(acc[mi][ni][0] + bb);
          dst[64]  = f2bf(acc[mi][ni][1] + bb);
          dst[128] = f2bf(acc[mi][ni][2] + bb);
          dst[192] = f2bf(acc[mi][ni][3] + bb);
        }
    } else {
      u16* ct = (u16*)sm;
      #pragma unroll
      for (int mi = 0; mi < 2; mi++)
        #pragma unroll
        for (int ni = 0; ni < 4; ni++) {
          int nr = nW + ni * 16 + l15;
          int mr = mW + mi * 16 + g * 4;
          float bb = bias[nBase + nr];
          u32 lo = (u32)f2bf(acc[mi][ni][0] + bb) | ((u32)f2bf(acc[mi][ni][1] + bb) << 16);
          u32 hi = (u32)f2bf(acc[mi][ni][2] + bb) | ((u32)f2bf(acc[mi][ni][3] + bb) << 16);
          *(u64*)(ct + nr * 72 + mr) = (u64)lo | ((u64)hi << 32);
        }
      __syncthreads();
      int dr = tid >> 1, part = tid & 1;
      int hn = (bx - 12) * 128 + dr;
      int h = hn >> 6, d = hn & 63;
      long bh = (long)b_ * 12 + h;
      u16* dst = Vtb + (bh << 16) + (d << 10) + s0b + part * 32;
      const u16* srl = ct + dr * 72 + part * 32;
      #pragma unroll
      for (int i = 0; i < 4; i++)
        *(uint4*)(dst + i * 8) = *(const uint4*)(srl + i * 8);
    }
  }
}

// ---------------- K2 (unchanged): extended features + beta, LOG2E folded ----------------
__global__ __launch_bounds__(256) void qk_ext_kernel(
    const u16* __restrict__ Qb, const u16* __restrict__ Kb, const float* __restrict__ Am,
    const float* __restrict__ mask, u16* __restrict__ qAe, u16* __restrict__ kAe,
    float* __restrict__ beta2)
{
  const bool isK = blockIdx.x >= 192;
  const int rb = blockIdx.x * 256 - (isK ? 49152 : 0);
  const int h = (rb >> 10) % 12;
  const int row = rb + threadIdx.x;
  const int bh = row >> 10;
  const int s = row & 1023;
  const int b_ = bh / 12;

  const u16* src = (isK ? Kb : Qb) + ((long)row << 6);
  union { uint4 v4[8]; u32 u[32]; } c;
  #pragma unroll
  for (int i = 0; i < 8; i++) c.v4[i] = ((const uint4*)src)[i];

  const float* Ah = Am + h * 1024;
  float acc[16];
  #pragma unroll
  for (int r = 0; r < 16; r++) acc[r] = 0.f;
  float s2 = 0.f;
  #pragma unroll
  for (int d = 0; d < 64; d++) {
    u32 wd = c.u[d >> 1];
    float qd = bf2f((u16)((d & 1) ? (wd >> 16) : (wd & 0xffffu)));
    s2 += qd * qd;
    #pragma unroll
    for (int r = 0; r < 16; r++) acc[r] += qd * Ah[d * 16 + r];
  }

  union { u16 us[128]; uint4 v4[16]; } o;
  const float sA = isK ? 1.0f : 0.25f * LOG2E;
  const float sQ = isK ? 1e-3f : 0.25e-3f * LOG2E;
  #pragma unroll
  for (int r = 0; r < 16; r++) o.us[r] = f2bf(acc[r] * sA);
  #pragma unroll
  for (int d = 0; d < 64; d++) {
    u32 wd = c.u[d >> 1];
    float qd = bf2f((u16)((d & 1) ? (wd >> 16) : (wd & 0xffffu)));
    o.us[16 + d] = f2bf(qd * sQ);
  }
  #pragma unroll
  for (int j = 80; j < 128; j++) o.us[j] = 0;

  u16* dst = (isK ? kAe : qAe) + ((long)row << 7);
  #pragma unroll
  for (int i = 0; i < 16; i++) ((uint4*)dst)[i] = o.v4[i];

  if (isK) {
    float kk = 1e-6f * s2;
    #pragma unroll
    for (int r = 0; r < 16; r++) kk += acc[r] * acc[r];
    beta2[row] = LOG2E * (-0.125f * kk + mask[(b_ << 10) + s]);
  }
}

// ---------------- K3: attention v8 — R4 skeleton, CHUNK=64 ----------------
// grid 768 = 48 bh x 16 qtiles(64 rows), XCD-swizzled; block 128 = 2 waves,
// wave owns 32 q rows. 16 iterations of 64 t each.
// Per iter: loadV(c) 8 -> wait vmcnt(8) [K(c) landed] -> barrier ->
//           stage K(c+1) 8 (post-barrier slot: WAR-safe, R4-proven) ->
//           QK 24 MFMA -> wait vmcnt(8) [V(c) landed, K(c+1) in flight] ->
//           exp+pack -> P LDS -> PV 16 MFMA.
// Beta in LDS (prologue, 1024B/instr). Counted vmcnt never 0 until last iter.
__global__ __launch_bounds__(128, 2) void attn_kernel(
    const u16* __restrict__ qAe, const u16* __restrict__ kAe, const u16* __restrict__ Vtb,
    const float* __restrict__ beta2, u16* __restrict__ ctxb)
{
  const int tid = threadIdx.x;
  const int lane = tid & 63;
  const int w = tid >> 6;
  const int l15 = lane & 15, g = lane >> 4;
  const int wid = ((int)blockIdx.x & 7) * 96 + ((int)blockIdx.x >> 3);  // 768 = 8*96
  const int bh = wid >> 4;
  const int qt = wid & 15;
  const int q0 = qt * 64 + w * 32;

  // LDS: K dbuf 2x16384 | P 2 waves x 4608 (32 rows x 128B, stride 144) | beta 4096
  __shared__ __align__(16) char sm[46080];
  char* const kb0  = sm;
  char* const kb1  = sm + 16384;
  char* const Pw   = sm + 32768 + w * 4608;
  float* const Blds = (float*)(sm + 41984);

  const u16* qbase = qAe + ((long)(bh * 1024 + q0) << 7);
  const u16* kbase = kAe + ((long)bh << 17);
  const u16* vbase = Vtb + ((long)bh << 16);
  const float* betab = beta2 + (bh << 10);

  // prologue FIFO: [bqv 6][beta 4][K0 8] = 18
  u32x4 bqv[2][3];
  #pragma unroll
  for (int qf = 0; qf < 2; qf++)
    #pragma unroll
    for (int ks = 0; ks < 3; ks++) {
      const u16* a = qbase + ((qf * 16 + l15) << 7) + ks * 32 + g * 8;
      asm volatile("global_load_dwordx4 %0, %1, off" : "=v"(bqv[qf][ks]) : "v"(a));
    }
  #pragma unroll
  for (int i = 0; i < 4; i++)
    gl2lds16(betab + i * 256 + lane * 4, (char*)Blds + i * 1024);   // 1024B/instr

  // stage K chunk c (64 rows x 256B = 16 instrs, 8/wave), XOR-swizzled source
  auto stageK = [&](int c, char* buf) {
    const int t0 = c * 64;
    #pragma unroll
    for (int i2 = 0; i2 < 8; i2++) {
      int i = w * 8 + i2;
      int r = i * 4 + (lane >> 4);
      int col = ((lane & 15) ^ (r & 7)) * 8;          // pre-swizzled source (rule #21)
      gl2lds16(kbase + (long)(t0 + r) * 128 + col, buf + i * 1024);
    }
  };
  // V: 8 frags (2 k-slices x 4 d-frags) per 64-t chunk
  auto loadV = [&](int c, u32x4 (&dst)[8]) {
    const int t0 = c * 64;
    #pragma unroll
    for (int ks2 = 0; ks2 < 2; ks2++)
      #pragma unroll
      for (int df = 0; df < 4; df++) {
        const u16* a = vbase + ((df * 16 + l15) << 10) + t0 + ks2 * 32 + g * 8;
        asm volatile("global_load_dwordx4 %0, %1, off" : "=v"(dst[ks2 * 4 + df]) : "v"(a));
      }
  };

  f32x4 zero = {0.f, 0.f, 0.f, 0.f};
  f32x4 cacc[2][4];
  #pragma unroll
  for (int a = 0; a < 2; a++)
    #pragma unroll
    for (int b = 0; b < 4; b++) cacc[a][b] = zero;
  float rsum[2] = {0.f, 0.f};
  u32x4 vb[8];

  stageK(0, kb0);

  std::integral_constant<bool, false> Ff;
  std::integral_constant<bool, true>  Tt;

  auto iter = [&](auto LASTC, int c, const char* bufc, char* bufn) {
    constexpr bool LAST = decltype(LASTC)::value;
    loadV(c, vb);                                   // +8
    asm volatile("s_waitcnt vmcnt(8)" ::: "memory"); // K(c) landed (V(c) remains)
    asm volatile("s_barrier" ::: "memory");
    __builtin_amdgcn_sched_barrier(0);
    if constexpr (!LAST) stageK(c + 1, bufn);       // post-barrier: WAR-safe slot
    // phase A: S^T = K @ Q^T (24 MFMA, 12 ds_read_b128 swizzled)
    f32x4 sacc[4][2];
    #pragma unroll
    for (int tf = 0; tf < 4; tf++) { sacc[tf][0] = zero; sacc[tf][1] = zero; }
    #pragma unroll
    for (int tf = 0; tf < 4; tf++)
      #pragma unroll
      for (int ks = 0; ks < 3; ks++) {
        s16x8 ak = *(const s16x8*)(bufc + (tf * 16 + l15) * 256 +
                                   ((ks * 64 + g * 16) ^ ((l15 & 7) << 4)));
        s16x8 b0 = __builtin_bit_cast(s16x8, bqv[0][ks]);
        s16x8 b1 = __builtin_bit_cast(s16x8, bqv[1][ks]);
        sacc[tf][0] = __builtin_amdgcn_mfma_f32_16x16x32_bf16(ak, b0, sacc[tf][0], 0, 0, 0);
        sacc[tf][1] = __builtin_amdgcn_mfma_f32_16x16x32_bf16(ak, b1, sacc[tf][1], 0, 0, 0);
      }
    if constexpr (!LAST) asm volatile("s_waitcnt vmcnt(8)" ::: "memory");  // V(c) landed
    else                 asm volatile("s_waitcnt vmcnt(0)" ::: "memory");
    __builtin_amdgcn_sched_barrier(0);              // rule #18
    // softmax: P = 2^(S + beta) -> bf16 -> per-wave LDS [q][t], stride 144
    #pragma unroll
    for (int tf = 0; tf < 4; tf++) {
      f32x4 bb = *(const f32x4*)((const char*)Blds + c * 256 + tf * 64 + g * 16);
      #pragma unroll
      for (int qf = 0; qf < 2; qf++) {
        float e0, e1, e2, e3;
        asm("v_exp_f32 %0, %1" : "=v"(e0) : "v"(sacc[tf][qf][0] + bb[0]));
        asm("v_exp_f32 %0, %1" : "=v"(e1) : "v"(sacc[tf][qf][1] + bb[1]));
        asm("v_exp_f32 %0, %1" : "=v"(e2) : "v"(sacc[tf][qf][2] + bb[2]));
        asm("v_exp_f32 %0, %1" : "=v"(e3) : "v"(sacc[tf][qf][3] + bb[3]));
        rsum[qf] += (e0 + e1) + (e2 + e3);
        u32 p01, p23;
        asm("v_cvt_pk_bf16_f32 %0, %1, %2" : "=v"(p01) : "v"(e0), "v"(e1));
        asm("v_cvt_pk_bf16_f32 %0, %1, %2" : "=v"(p23) : "v"(e2), "v"(e3));
        u32x2 pk = {p01, p23};
        *(u32x2*)(Pw + (qf * 16 + l15) * 144 + tf * 32 + g * 8) = pk;
      }
    }
    // phase B: ctx += P @ V (16 MFMA; P from own-wave LDS, V in regs)
    #pragma unroll
    for (int qf = 0; qf < 2; qf++)
      #pragma unroll
      for (int ks2 = 0; ks2 < 2; ks2++) {
        s16x8 ap = *(const s16x8*)(Pw + (qf * 16 + l15) * 144 + ks2 * 64 + g * 16);
        #pragma unroll
        for (int df = 0; df < 4; df++) {
          s16x8 bv = __builtin_bit_cast(s16x8, vb[ks2 * 4 + df]);
          cacc[qf][df] = __builtin_amdgcn_mfma_f32_16x16x32_bf16(ap, bv, cacc[qf][df], 0, 0, 0);
        }
      }
  };

  #pragma unroll 1
  for (int c2 = 0; c2 < 7; c2++) {
    iter(Ff, 2 * c2,     kb0, kb1);
    iter(Ff, 2 * c2 + 1, kb1, kb0);
  }
  iter(Ff, 14, kb0, kb1);
  iter(Tt, 15, kb1, kb0);

  // epilogue: per-wave softmax normalize + write
  #pragma unroll
  for (int qf = 0; qf < 2; qf++) {
    rsum[qf] += __shfl_xor(rsum[qf], 16);
    rsum[qf] += __shfl_xor(rsum[qf], 32);
  }
  const int b_ = bh / 12, h = bh % 12;
  #pragma unroll
  for (int qf = 0; qf < 2; qf++) {
    #pragma unroll
    for (int j = 0; j < 4; j++) {
      float rs = __shfl(rsum[qf], g * 4 + j);
      float rinv = 1.0f / rs;
      int qg = q0 + qf * 16 + g * 4 + j;
      long base = ((long)(b_ * 1024 + qg)) * 768 + h * 64;
      #pragma unroll
      for (int df = 0; df < 4; df++)
        ctxb[base + df * 16 + l15] = f2bf(cacc[qf][df][j] * rinv);
    }
  }
}

// ---------------- launcher ----------------
extern "C" void kernel_launch(void* const* d_in, const int* in_sizes, int n_in,
                              void* d_out, int out_size, void* d_ws, size_t ws_size,
                              hipStream_t stream)
{
  (void)in_sizes; (void)n_in; (void)out_size; (void)ws_size;
  const float* hs   = (const float*)d_in[0];
  const float* mask = (const float*)d_in[1];
  const float* Wq   = (const float*)d_in[2];
  const float* bq   = (const float*)d_in[3];
  const float* Wk   = (const float*)d_in[4];
  const float* bk   = (const float*)d_in[5];
  const float* Wv   = (const float*)d_in[6];
  const float* bv   = (const float*)d_in[7];
  const float* Wo   = (const float*)d_in[8];
  const float* bo   = (const float*)d_in[9];
  const float* Am   = (const float*)d_in[10];
  float* out = (float*)d_out;

  char* p = (char*)d_ws;
  u16* hsb      = (u16*)p;   p += 6291456;
  u16* wqkvb    = (u16*)p;   p += 3538944;
  u16* wob      = (u16*)p;   p += 1179648;
  float* biasqkv= (float*)p; p += 9216;
  u16* Qb       = (u16*)p;   p += 6291456;
  u16* Kb       = (u16*)p;   p += 6291456;
  u16* Vtb      = (u16*)p;   p += 6291456;
  u16* qAeb     = (u16*)p;   p += 12582912;
  u16* kAeb     = (u16*)p;   p += 12582912;
  float* beta2  = (float*)p; p += 196608;
  u16* ctxb     = (u16*)p;   p += 6291456;

  convert_kernel<<<2688, 256, 0, stream>>>(hs, Wq, Wk, Wv, Wo, bq, bk, bv,
                                           hsb, wqkvb, wob, biasqkv);
  gemm_bt<0><<<1152, 256, 0, stream>>>(hsb, wqkvb, biasqkv,
                                       nullptr, Qb, Kb, Vtb);
  qk_ext_kernel<<<384, 256, 0, stream>>>(Qb, Kb, Am, mask, qAeb, kAeb, beta2);
  attn_kernel<<<768, 128, 0, stream>>>(qAeb, kAeb, Vtb, beta2, ctxb);
  gemm_bt<1><<<384, 256, 0, stream>>>(ctxb, wob, bo, out,
                                      nullptr, nullptr, nullptr);
}